// Round 7
// baseline (1301.315 us; speedup 1.0000x reference)
//
#include <hip/hip_runtime.h>

typedef unsigned short u16;
typedef unsigned int u32;
typedef __attribute__((ext_vector_type(8))) _Float16 f16x8;  // 8 fp16 = 4 VGPRs
typedef __attribute__((ext_vector_type(4))) float f32x4;
typedef __attribute__((ext_vector_type(8))) u16 u16x8;

#define N_NODES 20000
#define N_EDGES 320000
#define F_IN 128
#define HID 256
#define OUT_F 32
#define N_LAYERS 30
#define N_GRAPHS 16
#define ELLCAP 64

// ---------------- fp16 helpers ----------------
__device__ __forceinline__ float h2f(u16 u) {
    _Float16 h;
    __builtin_memcpy(&h, &u, 2);
    return (float)h;
}
__device__ __forceinline__ u16 f2h(float f) {
    _Float16 h = (_Float16)f;
    u16 u;
    __builtin_memcpy(&u, &h, 2);
    return u;
}

__device__ __forceinline__ void gl_lds16(const u16* g, u16* l) {
    __builtin_amdgcn_global_load_lds((const u32*)g, (u32*)l, 16, 0, 0);
}

// ---------------- graph build ----------------
// fill_ell also produces the degree: cursor's final value == in-degree at dst.
// ell_col is pre-zeroed; unfilled slots stay 0 (node 0: valid, masked off in agg).
__global__ void fill_ell_kernel(const int* __restrict__ src, const int* __restrict__ dst,
                                int* __restrict__ cursor, u16* __restrict__ ell_col, int E) {
    int e = blockIdx.x * blockDim.x + threadIdx.x;
    if (e >= E) return;
    int s = src[e], d = dst[e];
    int slot = atomicAdd(&cursor[d], 1);
    if (slot < ELLCAP) ell_col[d * ELLCAP + slot] = (u16)s;
}

__global__ void dinv_kernel(const int* __restrict__ cnt, float* __restrict__ dinv, int n) {
    int i = blockIdx.x * blockDim.x + threadIdx.x;
    if (i < n) dinv[i] = rsqrtf((float)(cnt[i] + 1));  // +1 self loop
}

// x' = fp16(dinv ⊙ x): layer-1 gather source (fp16 = the measured numerics floor;
// fp8 failed at 9.3e-6 vs threshold 1.86e-7, R4)
__global__ void prescale_x_kernel(const float* __restrict__ x, const int* __restrict__ cnt,
                                  u16* __restrict__ xs, int total) {
    int i = blockIdx.x * 256 + threadIdx.x;
    if (i < total) xs[i] = f2h(x[i] * rsqrtf((float)(cnt[i >> 7] + 1)));   // F_IN = 128
}

// ---------------- weight transpose to fp16 (LDS-tiled, coalesced writes) ----------------
// W [L][K][N] (f32) -> T [L][N][K] (fp16); 32x32 tiles.
__global__ __launch_bounds__(256) void transpose_f16_tiled(const float* __restrict__ W,
                                                           u16* __restrict__ T,
                                                           int K, int N) {
    __shared__ float tile[32][33];
    const int l = blockIdx.y;
    const int ntn = N >> 5;
    const int kt = blockIdx.x / ntn, ntile = blockIdx.x % ntn;
    const float* Wl = W + (size_t)l * K * N;
    u16* Tl = T + (size_t)l * K * N;
    const int r8 = threadIdx.x >> 5, c = threadIdx.x & 31;
    #pragma unroll
    for (int rr = 0; rr < 4; ++rr) {
        int r = rr * 8 + r8;
        tile[r][c] = Wl[(size_t)(kt * 32 + r) * N + ntile * 32 + c];
    }
    __syncthreads();
    #pragma unroll
    for (int rr = 0; rr < 4; ++rr) {
        int n = rr * 8 + r8;                 // transposed row (N dim)
        float v = tile[c][n];                // W[k=kt*32+c][n]
        Tl[(size_t)(ntile * 32 + n) * K + kt * 32 + c] = f2h(v);
    }
}

// ---------------- fused layer, slice-interleaved (R7) ----------------
// One kernel per GCN layer. Block = 32 nodes, 256 threads (4 waves). Grid = 625.
//
// R6 ran all-gather then all-GEMM per block; touch-census model (gather 160K +
// Bs 80K + misc 20K = 260K line-touches/XCD/layer at ~14K/us service rate = 18.6us
// floor vs ~26us busy) says ~30% of time the L2 touch pipe idles while co-resident
// blocks sit in GEMM phase. R7: interleave per 64-feature slice p:
//   { issue Bs(p) stage -> gather slice p (long, hides Bs latency) -> barrier
//     -> GEMM k-step p from gs+Bs -> barrier }
// Blocks de-phase at 4x finer grain -> touch pipe stays fed. gs shrinks to ONE
// slice (4KB, consumed immediately): LDS = cols 4 + gs 4 + Bs 32 = 40KB ->
// 4 blocks/CU, 16 waves (was 3/12). Gather flattened to depth-1 (8-wide load ILP
// within a batch) to fit the 128-VGPR/wave budget of 4 waves/SIMD; added TLP
// replaces the dropped ILP.
// NUMERICS: accumulation order (self -> batches ascending -> masked tail) and
// GEMM k-order are bit-identical to R6 -> absmax must be exactly 1.490116e-7.
template <int K>
__global__ __launch_bounds__(256, 4) void layer_fused(const u16* __restrict__ hs,
                                                      const u16* __restrict__ B,
                                                      const u16* __restrict__ ell_col,
                                                      const int* __restrict__ cnt,
                                                      const float* __restrict__ dinv,
                                                      const float* __restrict__ bias,
                                                      const float* __restrict__ rowscale,
                                                      u16* __restrict__ Ch,
                                                      float* __restrict__ C) {
    __shared__ u16 cols[32 * ELLCAP];                 // 4 KB
    __shared__ __align__(16) u16 gs[32 * 64];         // 4 KB, one 64-feature slice
    __shared__ __align__(16) u16 Bs[256 * 64];        // 32 KB, n-major [256][64k]
    const int node0 = blockIdx.x * 32;
    const int tid = threadIdx.x;
    *(u16x8*)&cols[tid * 8] = *(const u16x8*)&ell_col[(size_t)node0 * ELLCAP + tid * 8];
    const int nd = tid >> 3, sub = tid & 7;
    const int node = node0 + nd;
    int c = cnt[node]; c = c < ELLCAP ? c : ELLCAP;
    const float dd = dinv[node];
    const int wave = tid >> 6, lane = tid & 63;
    const int lr = lane >> 3, lc = lane & 7;
    f32x4 acc[2][4] = {};
    __syncthreads();                                   // cols staged
    const u16* cl = &cols[nd * ELLCAP];
    const int nb = (c + 7) >> 3;                       // 8-batches (last masked)

    #pragma unroll 1
    for (int p = 0; p < K / 64; ++p) {
        const int kb = p * 64;
        // issue Bs(p) stage: 256 n-rows x 64 k, pre-swizzled src + linear dest;
        // latency hides under the gather below. Safe vs GEMM(p-1): barrier at end
        // of previous iteration ordered all reads of Bs before these writes.
        #pragma unroll
        for (int q = 0; q < 8; ++q) {
            int rl = (wave * 8 + q) * 8 + lr;          // B row (n), 0..255
            gl_lds16(B + (size_t)rl * K + kb + ((lc ^ (rl & 7)) << 3), &Bs[(wave * 8 + q) * 512]);
        }
        // ---- gather slice p (order identical to R6: self, batches asc, masked tail)
        const int f = kb + sub * 8;
        f32x4 a0 = {}, a1 = {};
        {   // self loop (pre-scaled)
            u16x8 sv = *(const u16x8*)(hs + (size_t)node * K + f);
            #pragma unroll
            for (int i = 0; i < 4; ++i) a0[i] += h2f(sv[i]);
            #pragma unroll
            for (int i = 0; i < 4; ++i) a1[i] += h2f(sv[i + 4]);
        }
        for (int b = 0; b < nb - 1; ++b) {             // full batches
            u16x8 cc = *(const u16x8*)&cl[b * 8];
            u16x8 v[8];
            #pragma unroll
            for (int j = 0; j < 8; ++j) v[j] = *(const u16x8*)(hs + (size_t)cc[j] * K + f);
            #pragma unroll
            for (int j = 0; j < 8; ++j) {
                #pragma unroll
                for (int i = 0; i < 4; ++i) a0[i] += h2f(v[j][i]);
                #pragma unroll
                for (int i = 0; i < 4; ++i) a1[i] += h2f(v[j][i + 4]);
            }
        }
        if (nb > 0) {                                  // final masked batch
            const int base = (nb - 1) * 8;
            u16x8 cc = *(const u16x8*)&cl[base];
            u16x8 v[8];
            #pragma unroll
            for (int j = 0; j < 8; ++j) v[j] = *(const u16x8*)(hs + (size_t)cc[j] * K + f);
            const u16x8 zz = {};
            #pragma unroll
            for (int j = 0; j < 8; ++j) {
                u16x8 vv = (base + j < c) ? v[j] : zz;
                #pragma unroll
                for (int i = 0; i < 4; ++i) a0[i] += h2f(vv[i]);
                #pragma unroll
                for (int i = 0; i < 4; ++i) a1[i] += h2f(vv[i + 4]);
            }
        }
        u16x8 o;
        #pragma unroll
        for (int i = 0; i < 4; ++i) o[i] = f2h(a0[i] * dd);
        #pragma unroll
        for (int i = 0; i < 4; ++i) o[i + 4] = f2h(a1[i] * dd);
        *(u16x8*)&gs[nd * 64 + ((sub ^ (nd & 7)) << 3)] = o;   // slice-local XOR swizzle

        __syncthreads();                               // gs written + Bs vmcnt drained
        // ---- GEMM k-step p (same MFMA order as R6)
        #pragma unroll
        for (int kk = 0; kk < 2; ++kk) {
            const int c8 = kk * 4 + (lane >> 4);       // 8-elem chunk within slice, 0..7
            f16x8 bf[4];
            #pragma unroll
            for (int nt = 0; nt < 4; ++nt) {
                int n = wave * 64 + nt * 16 + (lane & 15);
                bf[nt] = *(const f16x8*)&Bs[n * 64 + ((c8 ^ (n & 7)) << 3)];
            }
            #pragma unroll
            for (int mt = 0; mt < 2; ++mt) {
                int ml = mt * 16 + (lane & 15);
                f16x8 af = *(const f16x8*)&gs[ml * 64 + ((c8 ^ (ml & 7)) << 3)];
                #pragma unroll
                for (int nt = 0; nt < 4; ++nt)
                    acc[mt][nt] = __builtin_amdgcn_mfma_f32_16x16x32_f16(af, bf[nt], acc[mt][nt], 0, 0, 0);
            }
        }
        __syncthreads();                               // gs/Bs reusable next slice
    }
    // epilogue: bias + relu (+ dinv row scale); C/D layout col=lane&15, row=(lane>>4)*4+r
    #pragma unroll
    for (int mt = 0; mt < 2; ++mt) {
        int gr = node0 + mt * 16 + ((lane >> 4) << 2);
        #pragma unroll
        for (int r = 0; r < 4; ++r) {
            float sc = rowscale ? rowscale[gr + r] : 1.f;
            #pragma unroll
            for (int nt = 0; nt < 4; ++nt) {
                int gc = wave * 64 + nt * 16 + (lane & 15);
                float v = sc * fmaxf(acc[mt][nt][r] + bias[gc], 0.f);
                if (Ch) Ch[(size_t)(gr + r) * HID + gc] = f2h(v);
                else    C[(size_t)(gr + r) * HID + gc] = v;
            }
        }
    }
}

// ---------------- pooling ----------------
#define POOL_CHUNK 32
__global__ __launch_bounds__(256) void pool_kernel(const float* __restrict__ h,
                                                   const int* __restrict__ batch,
                                                   float* __restrict__ pool_sum) {
    int f = threadIdx.x;
    int start = blockIdx.x * POOL_CHUNK;
    int end = start + POOL_CHUNK; end = end < N_NODES ? end : N_NODES;
    if (start >= N_NODES) return;
    int gcur = batch[start];
    float acc = 0.f;
    for (int i = start; i < end; ++i) {
        int g = batch[i];
        if (g != gcur) { atomicAdd(&pool_sum[gcur * HID + f], acc); acc = 0.f; gcur = g; }
        acc += h[(size_t)i * HID + f];
    }
    atomicAdd(&pool_sum[gcur * HID + f], acc);
}

__device__ int lb_int(const int* __restrict__ a, int n, int v) {
    int lo = 0, hi = n;
    while (lo < hi) {
        int mid = (lo + hi) >> 1;
        if (a[mid] < v) lo = mid + 1; else hi = mid;
    }
    return lo;
}

__global__ void final_linear_kernel(const float* __restrict__ pool_sum,
                                    const int* __restrict__ batch,
                                    const float* __restrict__ Wlin,
                                    const float* __restrict__ blin,
                                    float* __restrict__ out) {
    int idx = blockIdx.x * blockDim.x + threadIdx.x;
    if (idx >= N_GRAPHS * OUT_F) return;
    int g = idx / OUT_F, o = idx % OUT_F;
    int lo = lb_int(batch, N_NODES, g);
    int hi = lb_int(batch, N_NODES, g + 1);
    float cinv = 1.f / fmaxf((float)(hi - lo), 1.f);
    float s = blin[o];
    for (int k = 0; k < HID; ++k) s += (pool_sum[g * HID + k] * cinv) * Wlin[k * OUT_F + o];
    out[idx] = s;
}

// ---------------- launch ----------------
static inline size_t align_up(size_t x, size_t a) { return (x + a - 1) & ~(a - 1); }

extern "C" void kernel_launch(void* const* d_in, const int* in_sizes, int n_in,
                              void* d_out, int out_size, void* d_ws, size_t ws_size,
                              hipStream_t stream) {
    const float* x     = (const float*)d_in[0];
    const int*   elist = (const int*)d_in[1];   // [2, E]
    const int*   batch = (const int*)d_in[2];
    const float* W1    = (const float*)d_in[3];
    const float* b1    = (const float*)d_in[4];
    const float* Wm    = (const float*)d_in[5];
    const float* bm    = (const float*)d_in[6];
    const float* Wlin  = (const float*)d_in[7];
    const float* blin  = (const float*)d_in[8];
    float* outp = (float*)d_out;

    const int* srcA = elist;
    const int* dstA = elist + N_EDGES;

    char* ws = (char*)d_ws;
    size_t off = 0;
    float* h      = (float*)(ws + off); off = align_up(off + sizeof(float) * N_NODES * HID, 1024);
    u16*   hA     = (u16*)(ws + off);   off = align_up(off + sizeof(u16) * N_NODES * HID, 1024);
    u16*   hB     = (u16*)(ws + off);   off = align_up(off + sizeof(u16) * N_NODES * HID, 1024);
    u16*   xs     = (u16*)(ws + off);   off = align_up(off + sizeof(u16) * N_NODES * F_IN, 1024);
    u16*   W1T    = (u16*)(ws + off);   off = align_up(off + sizeof(u16) * F_IN * HID, 1024);
    u16*   WmT    = (u16*)(ws + off);   off = align_up(off + sizeof(u16) * (N_LAYERS - 1) * HID * HID, 1024);
    int*   cursor = (int*)(ws + off);   off = align_up(off + sizeof(int) * N_NODES, 1024);
    float* dinv   = (float*)(ws + off); off = align_up(off + sizeof(float) * N_NODES, 1024);
    u16*   ell_col = (u16*)(ws + off);  off = align_up(off + sizeof(u16) * N_NODES * ELLCAP, 1024);
    float* pool_sum = (float*)(ws + off); off = align_up(off + sizeof(float) * N_GRAPHS * HID, 1024);

    hipMemsetAsync(cursor, 0, sizeof(int) * N_NODES, stream);
    hipMemsetAsync(ell_col, 0, sizeof(u16) * N_NODES * ELLCAP, stream);  // pad slots -> node 0 (masked)
    hipMemsetAsync(pool_sum, 0, sizeof(float) * N_GRAPHS * HID, stream);

    fill_ell_kernel<<<(N_EDGES + 255) / 256, 256, 0, stream>>>(srcA, dstA, cursor, ell_col, N_EDGES);
    dinv_kernel<<<(N_NODES + 255) / 256, 256, 0, stream>>>(cursor, dinv, N_NODES);
    prescale_x_kernel<<<(N_NODES * F_IN + 255) / 256, 256, 0, stream>>>(x, cursor, xs, N_NODES * F_IN);

    transpose_f16_tiled<<<dim3((F_IN / 32) * (HID / 32), 1), 256, 0, stream>>>(W1, W1T, F_IN, HID);
    transpose_f16_tiled<<<dim3((HID / 32) * (HID / 32), N_LAYERS - 1), 256, 0, stream>>>(Wm, WmT, HID, HID);

    const int lgrid = N_NODES / 32;   // 625, exact
    // layer 1: K = F_IN, gather from xs, write fp16 hA (double-buffer ping-pong after)
    layer_fused<F_IN><<<lgrid, 256, 0, stream>>>(xs, W1T, ell_col, cursor, dinv, b1, dinv, hA, h);
    u16* cur = hA; u16* nxt = hB;
    for (int l = 0; l < N_LAYERS - 1; ++l) {
        const bool last = (l == N_LAYERS - 2);
        layer_fused<HID><<<lgrid, 256, 0, stream>>>(cur, WmT + (size_t)l * HID * HID,
                                                    ell_col, cursor, dinv,
                                                    bm + (size_t)l * HID,
                                                    last ? nullptr : dinv,
                                                    last ? nullptr : nxt, h);
        u16* t = cur; cur = nxt; nxt = t;
    }
    pool_kernel<<<(N_NODES + POOL_CHUNK - 1) / POOL_CHUNK, 256, 0, stream>>>(h, batch, pool_sum);
    final_linear_kernel<<<2, 256, 0, stream>>>(pool_sum, batch, Wlin, blin, outp);
}

// Round 8
// 948.076 us; speedup vs baseline: 1.3726x; 1.3726x over previous
//
#include <hip/hip_runtime.h>

typedef unsigned short u16;
typedef unsigned int u32;
typedef __attribute__((ext_vector_type(8))) _Float16 f16x8;  // 8 fp16 = 4 VGPRs
typedef __attribute__((ext_vector_type(4))) float f32x4;
typedef __attribute__((ext_vector_type(8))) u16 u16x8;

#define N_NODES 20000
#define N_EDGES 320000
#define F_IN 128
#define HID 256
#define OUT_F 32
#define N_LAYERS 30
#define N_GRAPHS 16
#define ELLCAP 64

// ---------------- fp16 helpers ----------------
__device__ __forceinline__ float h2f(u16 u) {
    _Float16 h;
    __builtin_memcpy(&h, &u, 2);
    return (float)h;
}
__device__ __forceinline__ u16 f2h(float f) {
    _Float16 h = (_Float16)f;
    u16 u;
    __builtin_memcpy(&u, &h, 2);
    return u;
}

__device__ __forceinline__ void gl_lds16(const u16* g, u16* l) {
    __builtin_amdgcn_global_load_lds((const u32*)g, (u32*)l, 16, 0, 0);
}

// ---------------- graph build ----------------
// fill_ell also produces the degree: cursor's final value == in-degree at dst.
// ell_col is pre-zeroed; unfilled slots stay 0 (node 0: valid, masked off in agg).
__global__ void fill_ell_kernel(const int* __restrict__ src, const int* __restrict__ dst,
                                int* __restrict__ cursor, u16* __restrict__ ell_col, int E) {
    int e = blockIdx.x * blockDim.x + threadIdx.x;
    if (e >= E) return;
    int s = src[e], d = dst[e];
    int slot = atomicAdd(&cursor[d], 1);
    if (slot < ELLCAP) ell_col[d * ELLCAP + slot] = (u16)s;
}

__global__ void dinv_kernel(const int* __restrict__ cnt, float* __restrict__ dinv, int n) {
    int i = blockIdx.x * blockDim.x + threadIdx.x;
    if (i < n) dinv[i] = rsqrtf((float)(cnt[i] + 1));  // +1 self loop
}

// x' = fp16(dinv ⊙ x): layer-1 gather source (fp16 = the measured numerics floor;
// fp8 failed at 9.3e-6 vs threshold 1.86e-7, R4)
__global__ void prescale_x_kernel(const float* __restrict__ x, const int* __restrict__ cnt,
                                  u16* __restrict__ xs, int total) {
    int i = blockIdx.x * 256 + threadIdx.x;
    if (i < total) xs[i] = f2h(x[i] * rsqrtf((float)(cnt[i >> 7] + 1)));   // F_IN = 128
}

// ---------------- weight transpose to fp16 (LDS-tiled, coalesced writes) ----------------
// W [L][K][N] (f32) -> T [L][N][K] (fp16); 32x32 tiles.
__global__ __launch_bounds__(256) void transpose_f16_tiled(const float* __restrict__ W,
                                                           u16* __restrict__ T,
                                                           int K, int N) {
    __shared__ float tile[32][33];
    const int l = blockIdx.y;
    const int ntn = N >> 5;
    const int kt = blockIdx.x / ntn, ntile = blockIdx.x % ntn;
    const float* Wl = W + (size_t)l * K * N;
    u16* Tl = T + (size_t)l * K * N;
    const int r8 = threadIdx.x >> 5, c = threadIdx.x & 31;
    #pragma unroll
    for (int rr = 0; rr < 4; ++rr) {
        int r = rr * 8 + r8;
        tile[r][c] = Wl[(size_t)(kt * 32 + r) * N + ntile * 32 + c];
    }
    __syncthreads();
    #pragma unroll
    for (int rr = 0; rr < 4; ++rr) {
        int n = rr * 8 + r8;                 // transposed row (N dim)
        float v = tile[c][n];                // W[k=kt*32+c][n]
        Tl[(size_t)(ntile * 32 + n) * K + kt * 32 + c] = f2h(v);
    }
}

// ---------------- fused layer (R8 = R6 structure + XCD slice rotation + packed epilogue) ----------------
// One kernel per GCN layer. Block = 32 nodes, 256 threads (4 waves). Grid = 625.
// All 625 blocks are co-resident (< 768 = 256 CU x 3 blk) and start aligned.
//
// R7 counters (44us/layer): FETCH 58.5MB (h is 10.2MB -> per-XCD L2 thrash),
// WRITE 31.9MB (3x amplification from 2B scalar stores), VGPR 64 (bounds(,4)
// choked gather ILP), MfmaUtil 2% -> latency/L2-miss-bound, not touch-rate.
// R8 fixes, keeping R6's proven bulk-gather -> bulk-GEMM order:
//  (1) XCD-rotated slice order: block on XCD x (= blockIdx&7) gathers slice
//      (pi + x) & (S-1) at step pi. Row-major h: slice s of all nodes = line s
//      of each 512B row = 2.56MB, fits the 4MiB per-XCD L2. Aligned co-resident
//      blocks on one XCD hit the same slice window -> miss once per XCD per slice.
//      Slices are independent accumulate chains -> bit-identical h'.
//  (2) Packed epilogue: stage rounded/scaled outputs in LDS (XOR-swizzled cols),
//      then write full 128B lines (u16x8 fp16 / f32x4 last-layer). Same values,
//      same destinations -> bit-identical; WRITE 31.9 -> ~10.5MB.
// NUMERICS: absmax must be exactly 1.490116e-07 (R6 value); deviation = bug.
template <int K>
__global__ __launch_bounds__(256, 3) void layer_fused(const u16* __restrict__ hs,
                                                      const u16* __restrict__ B,
                                                      const u16* __restrict__ ell_col,
                                                      const int* __restrict__ cnt,
                                                      const float* __restrict__ dinv,
                                                      const float* __restrict__ bias,
                                                      const float* __restrict__ rowscale,
                                                      u16* __restrict__ Ch,
                                                      float* __restrict__ C) {
    __shared__ u16 cols[32 * ELLCAP];                 // 4 KB
    __shared__ __align__(16) u16 gs[32 * HID];        // 16 KB: A-operand (32*K), then fp16 out-stage
    __shared__ __align__(16) u16 Bs[256 * 64];        // 32 KB: B n-major [256][64k], then f32 out-stage
    const int node0 = blockIdx.x * 32;
    const int tid = threadIdx.x;
    *(u16x8*)&cols[tid * 8] = *(const u16x8*)&ell_col[(size_t)node0 * ELLCAP + tid * 8];
    const int nd = tid >> 3, sub = tid & 7;
    const int node = node0 + nd;
    int c = cnt[node]; c = c < ELLCAP ? c : ELLCAP;
    const float dd = dinv[node];
    __syncthreads();                                   // cols staged
    const u16* cl = &cols[nd * ELLCAP];
    const int nb = (c + 7) >> 3;                       // 8-batches (last masked)
    constexpr int S = K / 64;                          // slices
    const int p0 = blockIdx.x & (S - 1);               // XCD-aligned rotation

    // ---- phase 1: aggregate into gs, slices in XCD-rotated order ----
    #pragma unroll 1
    for (int pi = 0; pi < S; ++pi) {
        const int p = (pi + p0) & (S - 1);
        const int f = p * 64 + sub * 8;
        f32x4 a0 = {}, a1 = {};
        {   // self loop (pre-scaled)
            u16x8 sv = *(const u16x8*)(hs + (size_t)node * K + f);
            #pragma unroll
            for (int i = 0; i < 4; ++i) a0[i] += h2f(sv[i]);
            #pragma unroll
            for (int i = 0; i < 4; ++i) a1[i] += h2f(sv[i + 4]);
        }
        if (nb > 0) {
            u16x8 vbuf[8];
            u16x8 cc = *(const u16x8*)&cl[0];
            #pragma unroll
            for (int j = 0; j < 8; ++j) vbuf[j] = *(const u16x8*)(hs + (size_t)cc[j] * K + f);
            int base = 0;
            for (int b = 1; b < nb; ++b) {
                u16x8 cn = *(const u16x8*)&cl[b * 8];
                u16x8 vn[8];
                #pragma unroll
                for (int j = 0; j < 8; ++j) vn[j] = *(const u16x8*)(hs + (size_t)cn[j] * K + f);
                #pragma unroll
                for (int j = 0; j < 8; ++j) {
                    #pragma unroll
                    for (int i = 0; i < 4; ++i) a0[i] += h2f(vbuf[j][i]);
                    #pragma unroll
                    for (int i = 0; i < 4; ++i) a1[i] += h2f(vbuf[j][i + 4]);
                }
                base += 8;
                #pragma unroll
                for (int j = 0; j < 8; ++j) vbuf[j] = vn[j];
            }
            const u16x8 zz = {};
            #pragma unroll
            for (int j = 0; j < 8; ++j) {
                u16x8 v = (base + j < c) ? vbuf[j] : zz;   // masked final batch
                #pragma unroll
                for (int i = 0; i < 4; ++i) a0[i] += h2f(v[i]);
                #pragma unroll
                for (int i = 0; i < 4; ++i) a1[i] += h2f(v[i + 4]);
            }
        }
        u16x8 o;
        #pragma unroll
        for (int i = 0; i < 4; ++i) o[i] = f2h(a0[i] * dd);
        #pragma unroll
        for (int i = 0; i < 4; ++i) o[i + 4] = f2h(a1[i] * dd);
        const int cc_ = p * 8 + sub;                   // global 8-elem chunk index
        *(u16x8*)&gs[nd * K + ((cc_ ^ (nd & 7)) << 3)] = o;
    }

    // ---- phase 2: GEMM (identical to R6) ----
    const int wave = tid >> 6, lane = tid & 63;
    const int lr = lane >> 3, lc = lane & 7;
    // early stage Bs(k0=0): latency hides under the agg drain + first barrier
    #pragma unroll
    for (int q = 0; q < 8; ++q) {
        int rl = (wave * 8 + q) * 8 + lr;              // B row (n), 0..255
        gl_lds16(B + (size_t)rl * K + ((lc ^ (rl & 7)) << 3), &Bs[(wave * 8 + q) * 512]);
    }
    f32x4 acc[2][4] = {};
    #pragma unroll
    for (int k = 0; k < S; ++k) {
        __syncthreads();                               // gs + Bs(k) ready (drains vmcnt)
        const int k0 = k * 64;
        #pragma unroll
        for (int kk = 0; kk < 2; ++kk) {
            const int c8 = kk * 4 + (lane >> 4);       // chunk within 64-k tile, 0..7
            f16x8 bf[4];
            #pragma unroll
            for (int nt = 0; nt < 4; ++nt) {
                int n = wave * 64 + nt * 16 + (lane & 15);
                bf[nt] = *(const f16x8*)&Bs[n * 64 + ((c8 ^ (n & 7)) << 3)];
            }
            #pragma unroll
            for (int mt = 0; mt < 2; ++mt) {
                int ml = mt * 16 + (lane & 15);
                int cg = (k0 >> 3) + c8;               // global chunk index
                f16x8 af = *(const f16x8*)&gs[ml * K + ((cg ^ (ml & 7)) << 3)];
                #pragma unroll
                for (int nt = 0; nt < 4; ++nt)
                    acc[mt][nt] = __builtin_amdgcn_mfma_f32_16x16x32_f16(af, bf[nt], acc[mt][nt], 0, 0, 0);
            }
        }
        if (k + 1 < S) {
            __syncthreads();                           // all waves done reading Bs(k)
            const int kn = k0 + 64;
            #pragma unroll
            for (int q = 0; q < 8; ++q) {
                int rl = (wave * 8 + q) * 8 + lr;
                gl_lds16(B + (size_t)rl * K + kn + ((lc ^ (rl & 7)) << 3), &Bs[(wave * 8 + q) * 512]);
            }
        }
    }
    // ---- epilogue: bias + relu (+ rowscale), LDS-staged full-line writes ----
    // C/D layout col=lane&15, row=(lane>>4)*4+r. Values identical to R6; only the
    // write path changes (stage -> pack -> 128B-line stores).
    __syncthreads();                                   // all GEMM reads of gs/Bs done
    if (Ch) {
        #pragma unroll
        for (int mt = 0; mt < 2; ++mt) {
            #pragma unroll
            for (int r = 0; r < 4; ++r) {
                int lrow = mt * 16 + ((lane >> 4) << 2) + r;
                float sc = rowscale ? rowscale[node0 + lrow] : 1.f;
                #pragma unroll
                for (int nt = 0; nt < 4; ++nt) {
                    int gc = wave * 64 + nt * 16 + (lane & 15);
                    float v = sc * fmaxf(acc[mt][nt][r] + bias[gc], 0.f);
                    gs[lrow * HID + (gc ^ ((lrow & 7) << 3))] = f2h(v);
                }
            }
        }
        __syncthreads();
        const int row = tid >> 3, colb = (tid & 7) * 32;
        #pragma unroll
        for (int j = 0; j < 4; ++j) {
            int cs = (colb + j * 8) ^ ((row & 7) << 3);
            *(u16x8*)(Ch + (size_t)(node0 + row) * HID + colb + j * 8) = *(const u16x8*)&gs[row * HID + cs];
        }
    } else {
        float* Bf = (float*)Bs;                        // 32 KB = 32 x 256 f32, exact
        #pragma unroll
        for (int mt = 0; mt < 2; ++mt) {
            #pragma unroll
            for (int r = 0; r < 4; ++r) {
                int lrow = mt * 16 + ((lane >> 4) << 2) + r;
                float sc = rowscale ? rowscale[node0 + lrow] : 1.f;
                #pragma unroll
                for (int nt = 0; nt < 4; ++nt) {
                    int gc = wave * 64 + nt * 16 + (lane & 15);
                    float v = sc * fmaxf(acc[mt][nt][r] + bias[gc], 0.f);
                    Bf[lrow * HID + (gc ^ ((lrow & 7) << 2))] = v;
                }
            }
        }
        __syncthreads();
        const int row = tid >> 3, colb = (tid & 7) * 32;
        #pragma unroll
        for (int j = 0; j < 8; ++j) {
            int cs = (colb + j * 4) ^ ((row & 7) << 2);
            *(f32x4*)(C + (size_t)(node0 + row) * HID + colb + j * 4) = *(const f32x4*)&Bf[row * HID + cs];
        }
    }
}

// ---------------- pooling ----------------
#define POOL_CHUNK 32
__global__ __launch_bounds__(256) void pool_kernel(const float* __restrict__ h,
                                                   const int* __restrict__ batch,
                                                   float* __restrict__ pool_sum) {
    int f = threadIdx.x;
    int start = blockIdx.x * POOL_CHUNK;
    int end = start + POOL_CHUNK; end = end < N_NODES ? end : N_NODES;
    if (start >= N_NODES) return;
    int gcur = batch[start];
    float acc = 0.f;
    for (int i = start; i < end; ++i) {
        int g = batch[i];
        if (g != gcur) { atomicAdd(&pool_sum[gcur * HID + f], acc); acc = 0.f; gcur = g; }
        acc += h[(size_t)i * HID + f];
    }
    atomicAdd(&pool_sum[gcur * HID + f], acc);
}

__device__ int lb_int(const int* __restrict__ a, int n, int v) {
    int lo = 0, hi = n;
    while (lo < hi) {
        int mid = (lo + hi) >> 1;
        if (a[mid] < v) lo = mid + 1; else hi = mid;
    }
    return lo;
}

__global__ void final_linear_kernel(const float* __restrict__ pool_sum,
                                    const int* __restrict__ batch,
                                    const float* __restrict__ Wlin,
                                    const float* __restrict__ blin,
                                    float* __restrict__ out) {
    int idx = blockIdx.x * blockDim.x + threadIdx.x;
    if (idx >= N_GRAPHS * OUT_F) return;
    int g = idx / OUT_F, o = idx % OUT_F;
    int lo = lb_int(batch, N_NODES, g);
    int hi = lb_int(batch, N_NODES, g + 1);
    float cinv = 1.f / fmaxf((float)(hi - lo), 1.f);
    float s = blin[o];
    for (int k = 0; k < HID; ++k) s += (pool_sum[g * HID + k] * cinv) * Wlin[k * OUT_F + o];
    out[idx] = s;
}

// ---------------- launch ----------------
static inline size_t align_up(size_t x, size_t a) { return (x + a - 1) & ~(a - 1); }

extern "C" void kernel_launch(void* const* d_in, const int* in_sizes, int n_in,
                              void* d_out, int out_size, void* d_ws, size_t ws_size,
                              hipStream_t stream) {
    const float* x     = (const float*)d_in[0];
    const int*   elist = (const int*)d_in[1];   // [2, E]
    const int*   batch = (const int*)d_in[2];
    const float* W1    = (const float*)d_in[3];
    const float* b1    = (const float*)d_in[4];
    const float* Wm    = (const float*)d_in[5];
    const float* bm    = (const float*)d_in[6];
    const float* Wlin  = (const float*)d_in[7];
    const float* blin  = (const float*)d_in[8];
    float* outp = (float*)d_out;

    const int* srcA = elist;
    const int* dstA = elist + N_EDGES;

    char* ws = (char*)d_ws;
    size_t off = 0;
    float* h      = (float*)(ws + off); off = align_up(off + sizeof(float) * N_NODES * HID, 1024);
    u16*   hA     = (u16*)(ws + off);   off = align_up(off + sizeof(u16) * N_NODES * HID, 1024);
    u16*   hB     = (u16*)(ws + off);   off = align_up(off + sizeof(u16) * N_NODES * HID, 1024);
    u16*   xs     = (u16*)(ws + off);   off = align_up(off + sizeof(u16) * N_NODES * F_IN, 1024);
    u16*   W1T    = (u16*)(ws + off);   off = align_up(off + sizeof(u16) * F_IN * HID, 1024);
    u16*   WmT    = (u16*)(ws + off);   off = align_up(off + sizeof(u16) * (N_LAYERS - 1) * HID * HID, 1024);
    int*   cursor = (int*)(ws + off);   off = align_up(off + sizeof(int) * N_NODES, 1024);
    float* dinv   = (float*)(ws + off); off = align_up(off + sizeof(float) * N_NODES, 1024);
    u16*   ell_col = (u16*)(ws + off);  off = align_up(off + sizeof(u16) * N_NODES * ELLCAP, 1024);
    float* pool_sum = (float*)(ws + off); off = align_up(off + sizeof(float) * N_GRAPHS * HID, 1024);

    hipMemsetAsync(cursor, 0, sizeof(int) * N_NODES, stream);
    hipMemsetAsync(ell_col, 0, sizeof(u16) * N_NODES * ELLCAP, stream);  // pad slots -> node 0 (masked)
    hipMemsetAsync(pool_sum, 0, sizeof(float) * N_GRAPHS * HID, stream);

    fill_ell_kernel<<<(N_EDGES + 255) / 256, 256, 0, stream>>>(srcA, dstA, cursor, ell_col, N_EDGES);
    dinv_kernel<<<(N_NODES + 255) / 256, 256, 0, stream>>>(cursor, dinv, N_NODES);
    prescale_x_kernel<<<(N_NODES * F_IN + 255) / 256, 256, 0, stream>>>(x, cursor, xs, N_NODES * F_IN);

    transpose_f16_tiled<<<dim3((F_IN / 32) * (HID / 32), 1), 256, 0, stream>>>(W1, W1T, F_IN, HID);
    transpose_f16_tiled<<<dim3((HID / 32) * (HID / 32), N_LAYERS - 1), 256, 0, stream>>>(Wm, WmT, HID, HID);

    const int lgrid = N_NODES / 32;   // 625, exact
    // layer 1: K = F_IN, gather from xs, write fp16 hA (double-buffer ping-pong after)
    layer_fused<F_IN><<<lgrid, 256, 0, stream>>>(xs, W1T, ell_col, cursor, dinv, b1, dinv, hA, h);
    u16* cur = hA; u16* nxt = hB;
    for (int l = 0; l < N_LAYERS - 1; ++l) {
        const bool last = (l == N_LAYERS - 2);
        layer_fused<HID><<<lgrid, 256, 0, stream>>>(cur, WmT + (size_t)l * HID * HID,
                                                    ell_col, cursor, dinv,
                                                    bm + (size_t)l * HID,
                                                    last ? nullptr : dinv,
                                                    last ? nullptr : nxt, h);
        u16* t = cur; cur = nxt; nxt = t;
    }
    pool_kernel<<<(N_NODES + POOL_CHUNK - 1) / POOL_CHUNK, 256, 0, stream>>>(h, batch, pool_sum);
    final_linear_kernel<<<2, 256, 0, stream>>>(pool_sum, batch, Wlin, blin, outp);
}